// Round 2
// 350.628 us; speedup vs baseline: 1.0762x; 1.0762x over previous
//
#include <hip/hip_runtime.h>
#include <hip/hip_bf16.h>
#include <cstdint>
#include <cstddef>

#define D_MODEL 2048
#define NH 32
#define NKV 8
#define HD 64
#define BB 2
#define LL 2048
#define EPS 1e-6f
#define MM (BB * LL)   // 4096
#define QS 3072        // fused qkv row stride
#define KO 2048        // k column offset in qkv
#define VO 2560        // v column offset in qkv

typedef __hip_bfloat16 bf16;
typedef short bf16x8 __attribute__((ext_vector_type(8)));
typedef short s16x4 __attribute__((ext_vector_type(4)));
typedef float f32x4 __attribute__((ext_vector_type(4)));

// ---- dtype helpers ---------------------------------------------------------
__device__ inline float4 ld_bf4u(const unsigned short* p) {
  const ushort4 u = *(const ushort4*)p;
  float4 r;
  r.x = __uint_as_float(((unsigned)u.x) << 16);
  r.y = __uint_as_float(((unsigned)u.y) << 16);
  r.z = __uint_as_float(((unsigned)u.z) << 16);
  r.w = __uint_as_float(((unsigned)u.w) << 16);
  return r;
}
__device__ inline float4 ld4_rt(const void* p, size_t i, bool f32) {
  if (f32) return *(const float4*)((const float*)p + i);
  return ld_bf4u((const unsigned short*)p + i);
}
__device__ inline float ld1_rt(const void* p, size_t i, bool f32) {
  if (f32) return ((const float*)p)[i];
  unsigned short u = ((const unsigned short*)p)[i];
  return __uint_as_float(((unsigned)u) << 16);
}
__device__ inline unsigned short f2bf(float f) {
  bf16 h = __float2bfloat16(f);  // RNE
  return *reinterpret_cast<unsigned short*>(&h);
}
__device__ inline float bfu2f(unsigned short u) {
  return __uint_as_float(((unsigned)u) << 16);
}
__device__ inline void store1(float* p, float v) { *p = v; }
__device__ inline void store1(unsigned short* p, float v) { *p = f2bf(v); }

// async global->LDS, 16 B per lane; LDS dest must be wave-uniform base + lane*16
__device__ inline void glds16(const unsigned short* g, unsigned short* l) {
  __builtin_amdgcn_global_load_lds(
      (const __attribute__((address_space(1))) unsigned int*)g,
      (__attribute__((address_space(3))) unsigned int*)l, 16, 0, 0);
}

// ---- per-input dtype detector (sampled, vectorized) ------------------------
__global__ __launch_bounds__(256) void detect_all(
    const unsigned short* p0, const unsigned short* p1, const unsigned short* p2,
    const unsigned short* p3, const unsigned short* p4, const unsigned short* p5,
    const unsigned short* p6, int* __restrict__ flags) {
  const unsigned short* ptrs[7] = {p0, p1, p2, p3, p4, p5, p6};
  const int b = blockIdx.x;
  const uint4* p = (const uint4*)ptrs[b];  // 8 words per uint4
  __shared__ int found;
  if (threadIdx.x == 0) found = 0;
  __syncthreads();
  int loc = 0;
#pragma unroll
  for (int it = 0; it < 16; ++it) {
    uint4 v = p[it * 256 + threadIdx.x];
    unsigned wds[4] = {v.x, v.y, v.z, v.w};
#pragma unroll
    for (int q = 0; q < 4; ++q) {
      unsigned lo = wds[q] & 0xFFFFu, hi = wds[q] >> 16;
      if (((lo >> 7) & 0xFFu) == 0xFFu || ((hi >> 7) & 0xFFu) == 0xFFu) loc = 1;
    }
  }
  if (loc) atomicOr(&found, 1);
  __syncthreads();
  if (threadIdx.x == 0) flags[b] = found;
}

// ---- prep: elementwise convert to bf16 -------------------------------------
__global__ __launch_bounds__(256) void cvt_bf16(const void* __restrict__ src,
                                                unsigned short* __restrict__ dst,
                                                int n4, const int* __restrict__ flags, int idx) {
  const bool f32 = flags[idx] != 0;
  int i = blockIdx.x * 256 + threadIdx.x;
  if (i < n4) {
    float4 v = ld4_rt(src, (size_t)i * 4, f32);
    ushort4 o;
    o.x = f2bf(v.x); o.y = f2bf(v.y); o.z = f2bf(v.z); o.w = f2bf(v.w);
    *(ushort4*)&dst[(size_t)i * 4] = o;
  }
}

// ---- prep: transpose [K][N] -> [N][K] bf16 ---------------------------------
__global__ __launch_bounds__(256) void transpose_any(const void* __restrict__ src,
                                                     unsigned short* __restrict__ dst,
                                                     int K, int N,
                                                     const int* __restrict__ flags, int idx) {
  const bool f32 = flags[idx] != 0;
  __shared__ unsigned short tile[64][65];
  const int t = threadIdx.x;
  const int n0 = blockIdx.x * 64, k0 = blockIdx.y * 64;
  const int cr = t >> 4, cc = (t & 15) * 4;
#pragma unroll
  for (int rr = 0; rr < 4; ++rr) {
    int row = rr * 16 + cr;
    float4 v = ld4_rt(src, (size_t)(k0 + row) * N + n0 + cc, f32);
    tile[row][cc + 0] = f2bf(v.x);
    tile[row][cc + 1] = f2bf(v.y);
    tile[row][cc + 2] = f2bf(v.z);
    tile[row][cc + 3] = f2bf(v.w);
  }
  __syncthreads();
#pragma unroll
  for (int rr = 0; rr < 4; ++rr) {
    int nrow = rr * 16 + cr;
    ushort4 o;
    o.x = tile[cc + 0][nrow];
    o.y = tile[cc + 1][nrow];
    o.z = tile[cc + 2][nrow];
    o.w = tile[cc + 3][nrow];
    *(ushort4*)&dst[(size_t)(n0 + nrow) * K + k0 + cc] = o;
  }
}

// ---- prep: V columns of qkv -> Vt[b][kvh][d=64][L] (bf16) ------------------
__global__ __launch_bounds__(256) void v_to_vt(const unsigned short* __restrict__ qkv,
                                               unsigned short* __restrict__ vt) {
  __shared__ unsigned short tile[64][72];
  const int t = threadIdx.x;
  const int l0 = blockIdx.x * 64;
  const int bk = blockIdx.y;  // b*NKV + kvh
  const int r = t >> 2, c16 = (t & 3) * 16;
  const int b = bk >> 3, kvh = bk & 7;
  const unsigned short* src = &qkv[(size_t)(b * LL + l0 + r) * QS + VO + kvh * 64 + c16];
  *(uint4*)&tile[r][c16] = *(const uint4*)&src[0];
  *(uint4*)&tile[r][c16 + 8] = *(const uint4*)&src[8];
  __syncthreads();
  unsigned short u[16];
#pragma unroll
  for (int j = 0; j < 16; ++j) u[j] = tile[c16 + j][r];
  unsigned short* dst = &vt[((size_t)bk * 64 + r) * LL + l0 + c16];
  *(uint4*)&dst[0] = *(uint4*)&u[0];
  *(uint4*)&dst[8] = *(uint4*)&u[8];
}

// ---------------------------------------------------------------------------
// MFMA GEMM (m97 structure): C[M,N] = A[M,K]@Bt[N,K]^T, bf16 in, CT out.
// 128x128 tile, BK=32, global_load_lds width-16 staging, 2-barrier K-loop.
// XCD-aware bijective blockIdx swizzle (nwg % 8 == 0 for all our launches).
// ---------------------------------------------------------------------------
template <typename CT>
__global__ __launch_bounds__(256) void gemm_mfma(const unsigned short* __restrict__ A,
                                                 const unsigned short* __restrict__ Bt,
                                                 CT* __restrict__ C,
                                                 int M, int N, int K, int lda) {
  __shared__ __align__(16) unsigned short As[128 * 32];  // row-major [128][32]
  __shared__ __align__(16) unsigned short Bs[128 * 32];
  const int t = threadIdx.x;
  const int lane = t & 63, w = t >> 6;
  const int wm = (w >> 1) * 64, wn = (w & 1) * 64;
  const int g = lane >> 4, m16 = lane & 15;
  // XCD swizzle: blocks resident on one XCD get a contiguous chunk of work ids
  const int nwg = gridDim.x * gridDim.y;
  const int orig = blockIdx.y * gridDim.x + blockIdx.x;
  const int swz = (orig & 7) * (nwg >> 3) + (orig >> 3);
  const int m0 = (swz / gridDim.x) * 128, n0 = (swz % gridDim.x) * 128;
  const unsigned short* gA = &A[(size_t)(m0 + (t >> 2)) * lda + (t & 3) * 8];
  const unsigned short* gB = &Bt[(size_t)(n0 + (t >> 2)) * K + (t & 3) * 8];
  unsigned short* lA = &As[t * 8];
  unsigned short* lB = &Bs[t * 8];
  f32x4 acc[4][4] = {};
  for (int k0 = 0; k0 < K; k0 += 32) {
    __syncthreads();  // prev iteration's frag reads done
    glds16(gA + k0, lA);
    glds16(gA + (size_t)64 * lda + k0, lA + 2048);
    glds16(gB + k0, lB);
    glds16(gB + (size_t)64 * K + k0, lB + 2048);
    __syncthreads();  // drains vmcnt -> staged data visible
    bf16x8 af[4], bfr[4];
#pragma unroll
    for (int i = 0; i < 4; ++i) af[i] = *(const bf16x8*)&As[(wm + i * 16 + m16) * 32 + g * 8];
#pragma unroll
    for (int j = 0; j < 4; ++j) bfr[j] = *(const bf16x8*)&Bs[(wn + j * 16 + m16) * 32 + g * 8];
#pragma unroll
    for (int i = 0; i < 4; ++i)
#pragma unroll
      for (int j = 0; j < 4; ++j)
        acc[i][j] = __builtin_amdgcn_mfma_f32_16x16x32_bf16(af[i], bfr[j], acc[i][j], 0, 0, 0);
  }
#pragma unroll
  for (int i = 0; i < 4; ++i)
#pragma unroll
    for (int j = 0; j < 4; ++j)
#pragma unroll
      for (int r = 0; r < 4; ++r) {
        int row = m0 + wm + i * 16 + g * 4 + r;
        int col = n0 + wn + j * 16 + m16;
        store1(&C[(size_t)row * N + col], acc[i][j][r]);
      }
}

// ---------------------------------------------------------------------------
// RoPE + RMSNorm in place on fused qkv [M][3072]. One wave per (b,l,head).
// ---------------------------------------------------------------------------
__global__ __launch_bounds__(256) void rope_rms(unsigned short* __restrict__ qkv,
                                                const void* __restrict__ cosp,
                                                const void* __restrict__ sinp,
                                                const int* __restrict__ flags) {
  const bool cf = flags[1] != 0, sf = flags[2] != 0;
  const int wid = blockIdx.x * 4 + (threadIdx.x >> 6);
  const int lane = threadIdx.x & 63;
  const int hh = wid % (NH + NKV);
  const int bl = wid / (NH + NKV);
  const int l = bl & (LL - 1);
  unsigned short* base = (hh < NH) ? &qkv[(size_t)bl * QS + hh * 64]
                                   : &qkv[(size_t)bl * QS + KO + (hh - NH) * 64];
  const int j = lane & 31;
  float c = ld1_rt(cosp, l * 32 + j, cf);
  float s = ld1_rt(sinp, l * 32 + j, sf);
  float val = bfu2f(base[lane]);
  float other = __shfl_xor(val, 32);
  float r = (lane < 32) ? fmaf(val, c, -(other * s)) : fmaf(val, c, other * s);
  float ss = r * r;
#pragma unroll
  for (int off = 32; off; off >>= 1) ss += __shfl_xor(ss, off);
  base[lane] = f2bf(r * rsqrtf(ss * (1.0f / HD) + EPS));
}

// ---------------------------------------------------------------------------
// MFMA causal GQA flash attention with STATIC-MAX softmax, v2.1:
//  - K and V^T staged via global_load_lds width-16 into linear [64][64] LDS,
//    XOR chunk-swizzle applied on the GLOBAL source address (rule #21) and
//    on the ds_read_b128 fragment reads.
//  - double-buffered K/V, ONE barrier per KV tile; prefetch of tile t+1
//    issued before compute of tile t.
//  - P stored transposed per-wave (Pt[key][qrow]) with 4 vector ds_write_b64,
//    read back as A-fragments via ds_read_b64_tr_b16. tr semantics (m156/m162):
//    NO internal lane offset -- each lane fetches 8 B at its OWN address and a
//    crossbar within each 16-lane group transposes; group addresses must be
//    contiguous at (l&15)*8 B. (R1 bug: lane stride was 2 B -> garbage P.)
// After RMSNorm |q|=|k|=8 => scores*0.125 in [-8.07, 8.07]; fixed m=8:
// p = exp(s*0.125 - 8). O written in-place over the q columns.
// ---------------------------------------------------------------------------
__global__ __launch_bounds__(256) void attn_mfma(unsigned short* __restrict__ qkv,
                                                 const unsigned short* __restrict__ vt) {
  __shared__ __align__(16) unsigned short Ks[2][64 * 64];  // [key][d], chunk-swizzled
  __shared__ __align__(16) unsigned short Vs[2][64 * 64];  // [d][key], chunk-swizzled
  __shared__ __align__(16) unsigned short Pt[4][64 * 16];  // per-wave P^T [key][qrow]
  const int t = threadIdx.x, lane = t & 63, w = t >> 6;
  const int g = lane >> 4, m16 = lane & 15;
  const int h = blockIdx.x, b = blockIdx.y;
  const int qt = (LL / 64 - 1) - blockIdx.z;  // longest blocks dispatch first
  const int kvh = h >> 2;
  const int q0 = qt * 64, qr0 = q0 + w * 16;

  bf16x8 qf0, qf1;
  {
    const unsigned short* qrow = &qkv[(size_t)(b * LL + qr0 + m16) * QS + h * 64 + g * 8];
    qf0 = *(const bf16x8*)&qrow[0];
    qf1 = *(const bf16x8*)&qrow[32];
  }
  f32x4 Oacc[4] = {};
  float lrow[4] = {0.f, 0.f, 0.f, 0.f};

  // staging geometry: each wave stages 16 rows of the K tile and 16 rows of
  // V^T per KV block, as 2 glds16 calls x 8 rows each. lane -> (row lr,
  // chunk lc) with lc XOR-pre-swizzled on the source side.
  const int lr = lane >> 3;            // row within the 8-row group
  const int lc = (lane & 7) ^ lr;      // swizzled source 16B chunk
  const unsigned short* gK = &qkv[(size_t)(b * LL) * QS + KO + kvh * 64 + lc * 8];
  const unsigned short* gV = &vt[((size_t)(b * NKV + kvh) * 64 + w * 16 + lr) * LL + lc * 8];
  const int dbase = w * 1024 + lane * 8;  // LDS dest (shorts): wave-linear
  const int nIter = q0 / 64 + 1;

  // prologue: stage tile 0 into buffer 0
#pragma unroll
  for (int c = 0; c < 2; ++c) {
    glds16(gK + (size_t)(w * 16 + c * 8 + lr) * QS, &Ks[0][dbase + c * 512]);
    glds16(gV + (size_t)c * 8 * LL, &Vs[0][dbase + c * 512]);
  }
  __syncthreads();  // vmcnt(0) drain included

  const int sw8 = (m16 & 7) * 8;  // read-side chunk swizzle (shorts)
  for (int it = 0; it < nIter; ++it) {
    const int j0 = it * 64;
    const int cur = it & 1;
    if (it + 1 < nIter) {  // prefetch next tile into the other buffer
      const int nj = j0 + 64;
#pragma unroll
      for (int c = 0; c < 2; ++c) {
        glds16(gK + (size_t)(nj + w * 16 + c * 8 + lr) * QS, &Ks[cur ^ 1][dbase + c * 512]);
        glds16(gV + (size_t)c * 8 * LL + nj, &Vs[cur ^ 1][dbase + c * 512]);
      }
    }
    const unsigned short* KsB = Ks[cur];
    const unsigned short* VsB = Vs[cur];

    // S = Q K^T
    f32x4 S[4];
#pragma unroll
    for (int jt = 0; jt < 4; ++jt) {
      const int rb = (jt * 16 + m16) * 64;
      bf16x8 kf0 = *(const bf16x8*)&KsB[rb + ((g * 8) ^ sw8)];
      bf16x8 kf1 = *(const bf16x8*)&KsB[rb + (((g + 4) * 8) ^ sw8)];
      f32x4 z = {0.f, 0.f, 0.f, 0.f};
      z = __builtin_amdgcn_mfma_f32_16x16x32_bf16(qf0, kf0, z, 0, 0, 0);
      S[jt] = __builtin_amdgcn_mfma_f32_16x16x32_bf16(qf1, kf1, z, 0, 0, 0);
    }
    // static-max softmax: p = exp(s/8 - 8); mask only on the diagonal tile
    if (j0 == q0) {
#pragma unroll
      for (int jt = 0; jt < 4; ++jt)
#pragma unroll
        for (int r = 0; r < 4; ++r) {
          int col = q0 + jt * 16 + m16;
          int row = qr0 + g * 4 + r;
          float p = __expf(fmaf(S[jt][r], 0.125f, -8.0f));
          p = (col <= row) ? p : 0.f;
          S[jt][r] = p;
          lrow[r] += p;
        }
    } else {
#pragma unroll
      for (int jt = 0; jt < 4; ++jt)
#pragma unroll
        for (int r = 0; r < 4; ++r) {
          float p = __expf(fmaf(S[jt][r], 0.125f, -8.0f));
          S[jt][r] = p;
          lrow[r] += p;
        }
    }
    // P -> per-wave Pt (transposed [key][qrow]): 4 vector b64 writes
#pragma unroll
    for (int jt = 0; jt < 4; ++jt) {
      ushort4 pw;
      pw.x = f2bf(S[jt][0]); pw.y = f2bf(S[jt][1]);
      pw.z = f2bf(S[jt][2]); pw.w = f2bf(S[jt][3]);
      *(ushort4*)&Pt[w][(jt * 16 + m16) * 16 + g * 4] = pw;
    }
    // A-fragment reload via hardware transpose read. Per-lane fetch address:
    // group g covers keys g*8..g*8+7 (128 B region), lane stride 8 B within
    // the group => base short index g*128 + m16*4. Crossbar delivers lane
    // (g,m16) elem j = Pt[(g*8+j)*16 + m16] = P[qrow=m16][key=g*8+j].
    s16x4 a0, a1, b0, b1;
    {
      __attribute__((address_space(3))) unsigned short* p3 =
          (__attribute__((address_space(3))) unsigned short*)&Pt[w][g * 128 + m16 * 4];
      unsigned paddr = (unsigned)(size_t)p3;
      asm volatile(
          "s_waitcnt lgkmcnt(0)\n\t"
          "ds_read_b64_tr_b16 %0, %4\n\t"
          "ds_read_b64_tr_b16 %1, %4 offset:128\n\t"
          "ds_read_b64_tr_b16 %2, %4 offset:1024\n\t"
          "ds_read_b64_tr_b16 %3, %4 offset:1152\n\t"
          "s_waitcnt lgkmcnt(0)"
          : "=&v"(a0), "=&v"(a1), "=&v"(b0), "=&v"(b1)
          : "v"(paddr)
          : "memory");
      __builtin_amdgcn_sched_barrier(0);  // rule #18: keep MFMAs below the wait
    }
    bf16x8 pf0 = __builtin_shufflevector(a0, a1, 0, 1, 2, 3, 4, 5, 6, 7);
    bf16x8 pf1 = __builtin_shufflevector(b0, b1, 0, 1, 2, 3, 4, 5, 6, 7);
    // O += P V
#pragma unroll
    for (int dt = 0; dt < 4; ++dt) {
      const int rb = (dt * 16 + m16) * 64;
      bf16x8 vf0 = *(const bf16x8*)&VsB[rb + ((g * 8) ^ sw8)];
      bf16x8 vf1 = *(const bf16x8*)&VsB[rb + (((g + 4) * 8) ^ sw8)];
      Oacc[dt] = __builtin_amdgcn_mfma_f32_16x16x32_bf16(pf0, vf0, Oacc[dt], 0, 0, 0);
      Oacc[dt] = __builtin_amdgcn_mfma_f32_16x16x32_bf16(pf1, vf1, Oacc[dt], 0, 0, 0);
    }
    // single barrier per tile: syncs waves AND drains prefetch vmcnt
    __syncthreads();
  }
  // epilogue: reduce l across the 16-lane column groups, normalize, store
  float inv[4];
#pragma unroll
  for (int r = 0; r < 4; ++r) {
#pragma unroll
    for (int off = 1; off < 16; off <<= 1) lrow[r] += __shfl_xor(lrow[r], off);
    inv[r] = 1.0f / lrow[r];
  }
#pragma unroll
  for (int dt = 0; dt < 4; ++dt)
#pragma unroll
    for (int r = 0; r < 4; ++r) {
      int row = qr0 + g * 4 + r;
      qkv[(size_t)(b * LL + row) * QS + h * 64 + dt * 16 + m16] = f2bf(Oacc[dt][r] * inv[r]);
    }
}

// ---------------------------------------------------------------------------
extern "C" void kernel_launch(void* const* d_in, const int* in_sizes, int n_in,
                              void* d_out, int out_size, void* d_ws, size_t ws_size,
                              hipStream_t stream) {
  const void* x = d_in[0];
  const void* cosp = d_in[1];
  const void* sinp = d_in[2];
  const void* Wq = d_in[3];
  const void* Wk = d_in[4];
  const void* Wv = d_in[5];
  const void* Wo = d_in[6];
  float* out = (float*)d_out;

  // ws (bf16): xb [4096][2048] | qkvb [4096][3072] | WqkvT [3072][2048]
  //          | WoT [2048][2048] | Vt [2*8][64][2048]
  char* w0 = (char*)d_ws;
  int* flags = (int*)w0;
  unsigned short* xb = (unsigned short*)(w0 + 256);
  unsigned short* qkvb = xb + (size_t)MM * 2048;
  unsigned short* WqkvT = qkvb + (size_t)MM * QS;
  unsigned short* WoT = WqkvT + (size_t)QS * 2048;
  unsigned short* vt = WoT + (size_t)2048 * 2048;

  detect_all<<<7, 256, 0, stream>>>(
      (const unsigned short*)x, (const unsigned short*)cosp, (const unsigned short*)sinp,
      (const unsigned short*)Wq, (const unsigned short*)Wk, (const unsigned short*)Wv,
      (const unsigned short*)Wo, flags);
  cvt_bf16<<<MM * 2048 / 4 / 256, 256, 0, stream>>>(x, xb, MM * 2048 / 4, flags, 0);
  transpose_any<<<dim3(2048 / 64, 2048 / 64), 256, 0, stream>>>(Wq, WqkvT, 2048, 2048, flags, 3);
  transpose_any<<<dim3(512 / 64, 2048 / 64), 256, 0, stream>>>(Wk, WqkvT + (size_t)KO * 2048, 2048, 512, flags, 4);
  transpose_any<<<dim3(512 / 64, 2048 / 64), 256, 0, stream>>>(Wv, WqkvT + (size_t)VO * 2048, 2048, 512, flags, 5);
  transpose_any<<<dim3(2048 / 64, 2048 / 64), 256, 0, stream>>>(Wo, WoT, 2048, 2048, flags, 6);
  // fused QKV projection: [4096,2048] @ [2048,3072] -> qkvb
  gemm_mfma<unsigned short><<<dim3(QS / 128, MM / 128), 256, 0, stream>>>(xb, WqkvT, qkvb, MM, QS, 2048, 2048);
  rope_rms<<<MM * (NH + NKV) / 4, 256, 0, stream>>>(qkvb, cosp, sinp, flags);
  // V^T materialization (V is untouched by rope/rms)
  v_to_vt<<<dim3(LL / 64, BB * NKV), 256, 0, stream>>>(qkvb, vt);
  // causal GQA attention, O in-place into q columns; longest qt first
  attn_mfma<<<dim3(NH, BB, LL / 64), 256, 0, stream>>>(qkvb, vt);
  // output projection: qkv's q columns (lda=3072) @ WoT -> f32 out
  gemm_mfma<float><<<dim3(2048 / 128, MM / 128), 256, 0, stream>>>(qkvb, WoT, out, MM, 2048, 2048, QS);
}

// Round 3
// 338.171 us; speedup vs baseline: 1.1159x; 1.0368x over previous
//
#include <hip/hip_runtime.h>
#include <hip/hip_bf16.h>
#include <cstdint>
#include <cstddef>

#define D_MODEL 2048
#define NH 32
#define NKV 8
#define HD 64
#define BB 2
#define LL 2048
#define EPS 1e-6f
#define MM (BB * LL)   // 4096
#define QS 3072        // fused qkv row stride
#define KO 2048        // k column offset in qkv
#define VO 2560        // v column offset in qkv

typedef __hip_bfloat16 bf16;
typedef short bf16x8 __attribute__((ext_vector_type(8)));
typedef short s16x4 __attribute__((ext_vector_type(4)));
typedef float f32x4 __attribute__((ext_vector_type(4)));

// ---- dtype helpers ---------------------------------------------------------
__device__ inline float4 ld_bf4u(const unsigned short* p) {
  const ushort4 u = *(const ushort4*)p;
  float4 r;
  r.x = __uint_as_float(((unsigned)u.x) << 16);
  r.y = __uint_as_float(((unsigned)u.y) << 16);
  r.z = __uint_as_float(((unsigned)u.z) << 16);
  r.w = __uint_as_float(((unsigned)u.w) << 16);
  return r;
}
__device__ inline float4 ld4_rt(const void* p, size_t i, bool f32) {
  if (f32) return *(const float4*)((const float*)p + i);
  return ld_bf4u((const unsigned short*)p + i);
}
__device__ inline float ld1_rt(const void* p, size_t i, bool f32) {
  if (f32) return ((const float*)p)[i];
  unsigned short u = ((const unsigned short*)p)[i];
  return __uint_as_float(((unsigned)u) << 16);
}
__device__ inline unsigned short f2bf(float f) {
  bf16 h = __float2bfloat16(f);  // RNE
  return *reinterpret_cast<unsigned short*>(&h);
}
__device__ inline float bfu2f(unsigned short u) {
  return __uint_as_float(((unsigned)u) << 16);
}
__device__ inline void store1(float* p, float v) { *p = v; }
__device__ inline void store1(unsigned short* p, float v) { *p = f2bf(v); }

// async global->LDS, 16 B per lane; LDS dest must be wave-uniform base + lane*16
__device__ inline void glds16(const unsigned short* g, unsigned short* l) {
  __builtin_amdgcn_global_load_lds(
      (const __attribute__((address_space(1))) unsigned int*)g,
      (__attribute__((address_space(3))) unsigned int*)l, 16, 0, 0);
}

// ---- per-input dtype detector (sampled, vectorized) ------------------------
__global__ __launch_bounds__(256) void detect_all(
    const unsigned short* p0, const unsigned short* p1, const unsigned short* p2,
    const unsigned short* p3, const unsigned short* p4, const unsigned short* p5,
    const unsigned short* p6, int* __restrict__ flags) {
  const unsigned short* ptrs[7] = {p0, p1, p2, p3, p4, p5, p6};
  const int b = blockIdx.x;
  const uint4* p = (const uint4*)ptrs[b];  // 8 words per uint4
  __shared__ int found;
  if (threadIdx.x == 0) found = 0;
  __syncthreads();
  int loc = 0;
#pragma unroll
  for (int it = 0; it < 16; ++it) {
    uint4 v = p[it * 256 + threadIdx.x];
    unsigned wds[4] = {v.x, v.y, v.z, v.w};
#pragma unroll
    for (int q = 0; q < 4; ++q) {
      unsigned lo = wds[q] & 0xFFFFu, hi = wds[q] >> 16;
      if (((lo >> 7) & 0xFFu) == 0xFFu || ((hi >> 7) & 0xFFu) == 0xFFu) loc = 1;
    }
  }
  if (loc) atomicOr(&found, 1);
  __syncthreads();
  if (threadIdx.x == 0) flags[b] = found;
}

// ---- prep: elementwise convert to bf16 -------------------------------------
__global__ __launch_bounds__(256) void cvt_bf16(const void* __restrict__ src,
                                                unsigned short* __restrict__ dst,
                                                int n4, const int* __restrict__ flags, int idx) {
  const bool f32 = flags[idx] != 0;
  int i = blockIdx.x * 256 + threadIdx.x;
  if (i < n4) {
    float4 v = ld4_rt(src, (size_t)i * 4, f32);
    ushort4 o;
    o.x = f2bf(v.x); o.y = f2bf(v.y); o.z = f2bf(v.z); o.w = f2bf(v.w);
    *(ushort4*)&dst[(size_t)i * 4] = o;
  }
}

// ---- prep: transpose [K][N] -> [N][K] bf16 ---------------------------------
__global__ __launch_bounds__(256) void transpose_any(const void* __restrict__ src,
                                                     unsigned short* __restrict__ dst,
                                                     int K, int N,
                                                     const int* __restrict__ flags, int idx) {
  const bool f32 = flags[idx] != 0;
  __shared__ unsigned short tile[64][65];
  const int t = threadIdx.x;
  const int n0 = blockIdx.x * 64, k0 = blockIdx.y * 64;
  const int cr = t >> 4, cc = (t & 15) * 4;
#pragma unroll
  for (int rr = 0; rr < 4; ++rr) {
    int row = rr * 16 + cr;
    float4 v = ld4_rt(src, (size_t)(k0 + row) * N + n0 + cc, f32);
    tile[row][cc + 0] = f2bf(v.x);
    tile[row][cc + 1] = f2bf(v.y);
    tile[row][cc + 2] = f2bf(v.z);
    tile[row][cc + 3] = f2bf(v.w);
  }
  __syncthreads();
#pragma unroll
  for (int rr = 0; rr < 4; ++rr) {
    int nrow = rr * 16 + cr;
    ushort4 o;
    o.x = tile[cc + 0][nrow];
    o.y = tile[cc + 1][nrow];
    o.z = tile[cc + 2][nrow];
    o.w = tile[cc + 3][nrow];
    *(ushort4*)&dst[(size_t)(n0 + nrow) * K + k0 + cc] = o;
  }
}

// ---- prep: V columns of qkv -> Vt[b][kvh][d=64][L] (bf16) ------------------
__global__ __launch_bounds__(256) void v_to_vt(const unsigned short* __restrict__ qkv,
                                               unsigned short* __restrict__ vt) {
  __shared__ unsigned short tile[64][72];
  const int t = threadIdx.x;
  const int l0 = blockIdx.x * 64;
  const int bk = blockIdx.y;  // b*NKV + kvh
  const int r = t >> 2, c16 = (t & 3) * 16;
  const int b = bk >> 3, kvh = bk & 7;
  const unsigned short* src = &qkv[(size_t)(b * LL + l0 + r) * QS + VO + kvh * 64 + c16];
  *(uint4*)&tile[r][c16] = *(const uint4*)&src[0];
  *(uint4*)&tile[r][c16 + 8] = *(const uint4*)&src[8];
  __syncthreads();
  unsigned short u[16];
#pragma unroll
  for (int j = 0; j < 16; ++j) u[j] = tile[c16 + j][r];
  unsigned short* dst = &vt[((size_t)bk * 64 + r) * LL + l0 + c16];
  *(uint4*)&dst[0] = *(uint4*)&u[0];
  *(uint4*)&dst[8] = *(uint4*)&u[8];
}

// ---------------------------------------------------------------------------
// MFMA GEMM, 2-phase double-buffered (T3-minimum recipe):
//   prologue: stage tile0; barrier;
//   loop: issue stage(tile t+1, buf^1) FIRST; ds_read+MFMA on buf; barrier.
// Prefetch loads fly under the MFMAs; the single barrier (compiler emits
// s_waitcnt vmcnt(0) before s_barrier) makes them visible for the next iter.
// Buffer being written was last read two iterations ago -> WAR-safe.
// FUSE=1: QKV epilogue applies RoPE+RMSNorm in-register to q/k head columns
// (each wave's 64-col quadrant is exactly one head; rope pair (c,c+32) is
// acc[i][j] <-> acc[i][j^2], in-lane; RMS row-sum = 4 squares + 4 shfl_xor
// within the 16-lane row group).
// ---------------------------------------------------------------------------
template <typename CT, int FUSE>
__global__ __launch_bounds__(256) void gemm_mfma(const unsigned short* __restrict__ A,
                                                 const unsigned short* __restrict__ Bt,
                                                 CT* __restrict__ C,
                                                 int M, int N, int K, int lda,
                                                 const void* __restrict__ cosp,
                                                 const void* __restrict__ sinp,
                                                 const int* __restrict__ flags) {
  __shared__ __align__(16) unsigned short As[2][128 * 32];  // row-major [128][32]
  __shared__ __align__(16) unsigned short Bs[2][128 * 32];
  const int t = threadIdx.x;
  const int lane = t & 63, w = t >> 6;
  const int wm = (w >> 1) * 64, wn = (w & 1) * 64;
  const int g = lane >> 4, m16 = lane & 15;
  // XCD swizzle: blocks resident on one XCD get a contiguous chunk of work ids
  const int nwg = gridDim.x * gridDim.y;
  const int orig = blockIdx.y * gridDim.x + blockIdx.x;
  const int swz = (orig & 7) * (nwg >> 3) + (orig >> 3);
  const int m0 = (swz / gridDim.x) * 128, n0 = (swz % gridDim.x) * 128;
  const unsigned short* gA = &A[(size_t)(m0 + (t >> 2)) * lda + (t & 3) * 8];
  const unsigned short* gB = &Bt[(size_t)(n0 + (t >> 2)) * K + (t & 3) * 8];
  const int l8 = t * 8;
  f32x4 acc[4][4] = {};
  // prologue: stage tile 0 into buffer 0
  glds16(gA, &As[0][l8]);
  glds16(gA + (size_t)64 * lda, &As[0][l8 + 2048]);
  glds16(gB, &Bs[0][l8]);
  glds16(gB + (size_t)64 * K, &Bs[0][l8 + 2048]);
  __syncthreads();  // drains vmcnt -> tile 0 visible
  int cur = 0;
  for (int k0 = 0; k0 < K; k0 += 32) {
    if (k0 + 32 < K) {  // issue next-tile prefetch before compute
      glds16(gA + k0 + 32, &As[cur ^ 1][l8]);
      glds16(gA + (size_t)64 * lda + k0 + 32, &As[cur ^ 1][l8 + 2048]);
      glds16(gB + k0 + 32, &Bs[cur ^ 1][l8]);
      glds16(gB + (size_t)64 * K + k0 + 32, &Bs[cur ^ 1][l8 + 2048]);
    }
    bf16x8 af[4], bfr[4];
#pragma unroll
    for (int i = 0; i < 4; ++i) af[i] = *(const bf16x8*)&As[cur][(wm + i * 16 + m16) * 32 + g * 8];
#pragma unroll
    for (int j = 0; j < 4; ++j) bfr[j] = *(const bf16x8*)&Bs[cur][(wn + j * 16 + m16) * 32 + g * 8];
#pragma unroll
    for (int i = 0; i < 4; ++i)
#pragma unroll
      for (int j = 0; j < 4; ++j)
        acc[i][j] = __builtin_amdgcn_mfma_f32_16x16x32_bf16(af[i], bfr[j], acc[i][j], 0, 0, 0);
    __syncthreads();  // frag reads done + prefetch vmcnt drained
    cur ^= 1;
  }
  if constexpr (FUSE) {
    const int colbase = n0 + wn;          // 64-aligned -> exactly one head/wave
    if (colbase < VO) {                   // q or k head: RoPE + RMSNorm
      const bool cf = flags[1] != 0, sf = flags[2] != 0;
#pragma unroll
      for (int i = 0; i < 4; ++i)
#pragma unroll
        for (int r = 0; r < 4; ++r) {
          const int row = m0 + wm + i * 16 + g * 4 + r;
          const int l = row & (LL - 1);
          // pair indices for this lane: jj0 = m16 (cols m16, m16+32),
          //                             jj1 = 16+m16 (cols 16+m16, 48+m16)
          const float c0 = ld1_rt(cosp, l * 32 + m16, cf);
          const float c1 = ld1_rt(cosp, l * 32 + 16 + m16, cf);
          const float s0 = ld1_rt(sinp, l * 32 + m16, sf);
          const float s1 = ld1_rt(sinp, l * 32 + 16 + m16, sf);
          const float x0 = acc[i][0][r], x1 = acc[i][1][r];
          const float x2 = acc[i][2][r], x3 = acc[i][3][r];
          const float r0 = x0 * c0 - x2 * s0;
          const float r1 = x1 * c1 - x3 * s1;
          const float r2 = x2 * c0 + x0 * s0;
          const float r3 = x3 * c1 + x1 * s1;
          float ss = r0 * r0 + r1 * r1 + r2 * r2 + r3 * r3;
#pragma unroll
          for (int off = 1; off < 16; off <<= 1) ss += __shfl_xor(ss, off);
          const float sc = rsqrtf(ss * (1.0f / HD) + EPS);
          CT* cr = &C[(size_t)row * N + colbase + m16];
          store1(cr + 0, r0 * sc);
          store1(cr + 16, r1 * sc);
          store1(cr + 32, r2 * sc);
          store1(cr + 48, r3 * sc);
        }
      return;
    }
  }
#pragma unroll
  for (int i = 0; i < 4; ++i)
#pragma unroll
    for (int j = 0; j < 4; ++j)
#pragma unroll
      for (int r = 0; r < 4; ++r) {
        int row = m0 + wm + i * 16 + g * 4 + r;
        int col = n0 + wn + j * 16 + m16;
        store1(&C[(size_t)row * N + col], acc[i][j][r]);
      }
}

// ---------------------------------------------------------------------------
// MFMA causal GQA flash attention with STATIC-MAX softmax (unchanged from R2).
// ---------------------------------------------------------------------------
__global__ __launch_bounds__(256) void attn_mfma(unsigned short* __restrict__ qkv,
                                                 const unsigned short* __restrict__ vt) {
  __shared__ __align__(16) unsigned short Ks[2][64 * 64];  // [key][d], chunk-swizzled
  __shared__ __align__(16) unsigned short Vs[2][64 * 64];  // [d][key], chunk-swizzled
  __shared__ __align__(16) unsigned short Pt[4][64 * 16];  // per-wave P^T [key][qrow]
  const int t = threadIdx.x, lane = t & 63, w = t >> 6;
  const int g = lane >> 4, m16 = lane & 15;
  const int h = blockIdx.x, b = blockIdx.y;
  const int qt = (LL / 64 - 1) - blockIdx.z;  // longest blocks dispatch first
  const int kvh = h >> 2;
  const int q0 = qt * 64, qr0 = q0 + w * 16;

  bf16x8 qf0, qf1;
  {
    const unsigned short* qrow = &qkv[(size_t)(b * LL + qr0 + m16) * QS + h * 64 + g * 8];
    qf0 = *(const bf16x8*)&qrow[0];
    qf1 = *(const bf16x8*)&qrow[32];
  }
  f32x4 Oacc[4] = {};
  float lrow[4] = {0.f, 0.f, 0.f, 0.f};

  const int lr = lane >> 3;            // row within the 8-row group
  const int lc = (lane & 7) ^ lr;      // swizzled source 16B chunk
  const unsigned short* gK = &qkv[(size_t)(b * LL) * QS + KO + kvh * 64 + lc * 8];
  const unsigned short* gV = &vt[((size_t)(b * NKV + kvh) * 64 + w * 16 + lr) * LL + lc * 8];
  const int dbase = w * 1024 + lane * 8;  // LDS dest (shorts): wave-linear
  const int nIter = q0 / 64 + 1;

  // prologue: stage tile 0 into buffer 0
#pragma unroll
  for (int c = 0; c < 2; ++c) {
    glds16(gK + (size_t)(w * 16 + c * 8 + lr) * QS, &Ks[0][dbase + c * 512]);
    glds16(gV + (size_t)c * 8 * LL, &Vs[0][dbase + c * 512]);
  }
  __syncthreads();  // vmcnt(0) drain included

  const int sw8 = (m16 & 7) * 8;  // read-side chunk swizzle (shorts)
  for (int it = 0; it < nIter; ++it) {
    const int j0 = it * 64;
    const int cur = it & 1;
    if (it + 1 < nIter) {  // prefetch next tile into the other buffer
      const int nj = j0 + 64;
#pragma unroll
      for (int c = 0; c < 2; ++c) {
        glds16(gK + (size_t)(nj + w * 16 + c * 8 + lr) * QS, &Ks[cur ^ 1][dbase + c * 512]);
        glds16(gV + (size_t)c * 8 * LL + nj, &Vs[cur ^ 1][dbase + c * 512]);
      }
    }
    const unsigned short* KsB = Ks[cur];
    const unsigned short* VsB = Vs[cur];

    // S = Q K^T
    f32x4 S[4];
#pragma unroll
    for (int jt = 0; jt < 4; ++jt) {
      const int rb = (jt * 16 + m16) * 64;
      bf16x8 kf0 = *(const bf16x8*)&KsB[rb + ((g * 8) ^ sw8)];
      bf16x8 kf1 = *(const bf16x8*)&KsB[rb + (((g + 4) * 8) ^ sw8)];
      f32x4 z = {0.f, 0.f, 0.f, 0.f};
      z = __builtin_amdgcn_mfma_f32_16x16x32_bf16(qf0, kf0, z, 0, 0, 0);
      S[jt] = __builtin_amdgcn_mfma_f32_16x16x32_bf16(qf1, kf1, z, 0, 0, 0);
    }
    // static-max softmax: p = exp(s/8 - 8); mask only on the diagonal tile
    if (j0 == q0) {
#pragma unroll
      for (int jt = 0; jt < 4; ++jt)
#pragma unroll
        for (int r = 0; r < 4; ++r) {
          int col = q0 + jt * 16 + m16;
          int row = qr0 + g * 4 + r;
          float p = __expf(fmaf(S[jt][r], 0.125f, -8.0f));
          p = (col <= row) ? p : 0.f;
          S[jt][r] = p;
          lrow[r] += p;
        }
    } else {
#pragma unroll
      for (int jt = 0; jt < 4; ++jt)
#pragma unroll
        for (int r = 0; r < 4; ++r) {
          float p = __expf(fmaf(S[jt][r], 0.125f, -8.0f));
          S[jt][r] = p;
          lrow[r] += p;
        }
    }
    // P -> per-wave Pt (transposed [key][qrow]): 4 vector b64 writes
#pragma unroll
    for (int jt = 0; jt < 4; ++jt) {
      ushort4 pw;
      pw.x = f2bf(S[jt][0]); pw.y = f2bf(S[jt][1]);
      pw.z = f2bf(S[jt][2]); pw.w = f2bf(S[jt][3]);
      *(ushort4*)&Pt[w][(jt * 16 + m16) * 16 + g * 4] = pw;
    }
    // A-fragment reload via hardware transpose read (lane stride 8 B in-group)
    s16x4 a0, a1, b0, b1;
    {
      __attribute__((address_space(3))) unsigned short* p3 =
          (__attribute__((address_space(3))) unsigned short*)&Pt[w][g * 128 + m16 * 4];
      unsigned paddr = (unsigned)(size_t)p3;
      asm volatile(
          "s_waitcnt lgkmcnt(0)\n\t"
          "ds_read_b64_tr_b16 %0, %4\n\t"
          "ds_read_b64_tr_b16 %1, %4 offset:128\n\t"
          "ds_read_b64_tr_b16 %2, %4 offset:1024\n\t"
          "ds_read_b64_tr_b16 %3, %4 offset:1152\n\t"
          "s_waitcnt lgkmcnt(0)"
          : "=&v"(a0), "=&v"(a1), "=&v"(b0), "=&v"(b1)
          : "v"(paddr)
          : "memory");
      __builtin_amdgcn_sched_barrier(0);  // rule #18: keep MFMAs below the wait
    }
    bf16x8 pf0 = __builtin_shufflevector(a0, a1, 0, 1, 2, 3, 4, 5, 6, 7);
    bf16x8 pf1 = __builtin_shufflevector(b0, b1, 0, 1, 2, 3, 4, 5, 6, 7);
    // O += P V
#pragma unroll
    for (int dt = 0; dt < 4; ++dt) {
      const int rb = (dt * 16 + m16) * 64;
      bf16x8 vf0 = *(const bf16x8*)&VsB[rb + ((g * 8) ^ sw8)];
      bf16x8 vf1 = *(const bf16x8*)&VsB[rb + (((g + 4) * 8) ^ sw8)];
      Oacc[dt] = __builtin_amdgcn_mfma_f32_16x16x32_bf16(pf0, vf0, Oacc[dt], 0, 0, 0);
      Oacc[dt] = __builtin_amdgcn_mfma_f32_16x16x32_bf16(pf1, vf1, Oacc[dt], 0, 0, 0);
    }
    // single barrier per tile: syncs waves AND drains prefetch vmcnt
    __syncthreads();
  }
  // epilogue: reduce l across the 16-lane column groups, normalize, store
  float inv[4];
#pragma unroll
  for (int r = 0; r < 4; ++r) {
#pragma unroll
    for (int off = 1; off < 16; off <<= 1) lrow[r] += __shfl_xor(lrow[r], off);
    inv[r] = 1.0f / lrow[r];
  }
#pragma unroll
  for (int dt = 0; dt < 4; ++dt)
#pragma unroll
    for (int r = 0; r < 4; ++r) {
      int row = qr0 + g * 4 + r;
      qkv[(size_t)(b * LL + row) * QS + h * 64 + dt * 16 + m16] = f2bf(Oacc[dt][r] * inv[r]);
    }
}

// ---------------------------------------------------------------------------
extern "C" void kernel_launch(void* const* d_in, const int* in_sizes, int n_in,
                              void* d_out, int out_size, void* d_ws, size_t ws_size,
                              hipStream_t stream) {
  const void* x = d_in[0];
  const void* cosp = d_in[1];
  const void* sinp = d_in[2];
  const void* Wq = d_in[3];
  const void* Wk = d_in[4];
  const void* Wv = d_in[5];
  const void* Wo = d_in[6];
  float* out = (float*)d_out;

  // ws (bf16): xb [4096][2048] | qkvb [4096][3072] | WqkvT [3072][2048]
  //          | WoT [2048][2048] | Vt [2*8][64][2048]
  char* w0 = (char*)d_ws;
  int* flags = (int*)w0;
  unsigned short* xb = (unsigned short*)(w0 + 256);
  unsigned short* qkvb = xb + (size_t)MM * 2048;
  unsigned short* WqkvT = qkvb + (size_t)MM * QS;
  unsigned short* WoT = WqkvT + (size_t)QS * 2048;
  unsigned short* vt = WoT + (size_t)2048 * 2048;

  detect_all<<<7, 256, 0, stream>>>(
      (const unsigned short*)x, (const unsigned short*)cosp, (const unsigned short*)sinp,
      (const unsigned short*)Wq, (const unsigned short*)Wk, (const unsigned short*)Wv,
      (const unsigned short*)Wo, flags);
  cvt_bf16<<<MM * 2048 / 4 / 256, 256, 0, stream>>>(x, xb, MM * 2048 / 4, flags, 0);
  transpose_any<<<dim3(2048 / 64, 2048 / 64), 256, 0, stream>>>(Wq, WqkvT, 2048, 2048, flags, 3);
  transpose_any<<<dim3(512 / 64, 2048 / 64), 256, 0, stream>>>(Wk, WqkvT + (size_t)KO * 2048, 2048, 512, flags, 4);
  transpose_any<<<dim3(512 / 64, 2048 / 64), 256, 0, stream>>>(Wv, WqkvT + (size_t)VO * 2048, 2048, 512, flags, 5);
  transpose_any<<<dim3(2048 / 64, 2048 / 64), 256, 0, stream>>>(Wo, WoT, 2048, 2048, flags, 6);
  // fused QKV projection + RoPE + RMSNorm epilogue on q/k heads
  gemm_mfma<unsigned short, 1><<<dim3(QS / 128, MM / 128), 256, 0, stream>>>(
      xb, WqkvT, qkvb, MM, QS, 2048, 2048, cosp, sinp, flags);
  // V^T materialization (V is untouched by rope/rms)
  v_to_vt<<<dim3(LL / 64, BB * NKV), 256, 0, stream>>>(qkvb, vt);
  // causal GQA attention, O in-place into q columns; longest qt first
  attn_mfma<<<dim3(NH, BB, LL / 64), 256, 0, stream>>>(qkvb, vt);
  // output projection: qkv's q columns (lda=3072) @ WoT -> f32 out
  gemm_mfma<float, 0><<<dim3(2048 / 128, MM / 128), 256, 0, stream>>>(
      qkvb, WoT, out, MM, 2048, 2048, QS, nullptr, nullptr, nullptr);
}

// Round 4
// 327.475 us; speedup vs baseline: 1.1523x; 1.0327x over previous
//
#include <hip/hip_runtime.h>
#include <hip/hip_bf16.h>
#include <cstdint>
#include <cstddef>

#define D_MODEL 2048
#define NH 32
#define NKV 8
#define HD 64
#define BB 2
#define LL 2048
#define EPS 1e-6f
#define MM (BB * LL)   // 4096
#define QS 3072        // fused qkv row stride
#define KO 2048        // k column offset in qkv
#define VO 2560        // v column offset in qkv
// softmax fold: q pre-scaled by 0.125*log2(e); p = 2^(S - 8*log2(e))
#define QSCALE 0.18033688f
#define SM_BIAS 11.5415603f

typedef __hip_bfloat16 bf16;
typedef short bf16x8 __attribute__((ext_vector_type(8)));
typedef short s16x4 __attribute__((ext_vector_type(4)));
typedef float f32x4 __attribute__((ext_vector_type(4)));

// ---- dtype helpers ---------------------------------------------------------
__device__ inline float4 ld_bf4u(const unsigned short* p) {
  const ushort4 u = *(const ushort4*)p;
  float4 r;
  r.x = __uint_as_float(((unsigned)u.x) << 16);
  r.y = __uint_as_float(((unsigned)u.y) << 16);
  r.z = __uint_as_float(((unsigned)u.z) << 16);
  r.w = __uint_as_float(((unsigned)u.w) << 16);
  return r;
}
__device__ inline float4 ld4_rt(const void* p, size_t i, bool f32) {
  if (f32) return *(const float4*)((const float*)p + i);
  return ld_bf4u((const unsigned short*)p + i);
}
__device__ inline float ld1_rt(const void* p, size_t i, bool f32) {
  if (f32) return ((const float*)p)[i];
  unsigned short u = ((const unsigned short*)p)[i];
  return __uint_as_float(((unsigned)u) << 16);
}
__device__ inline unsigned short f2bf(float f) {
  bf16 h = __float2bfloat16(f);  // RNE
  return *reinterpret_cast<unsigned short*>(&h);
}
__device__ inline float bfu2f(unsigned short u) {
  return __uint_as_float(((unsigned)u) << 16);
}
__device__ inline void store1(float* p, float v) { *p = v; }
__device__ inline void store1(unsigned short* p, float v) { *p = f2bf(v); }

// async global->LDS, 16 B per lane; LDS dest must be wave-uniform base + lane*16
__device__ inline void glds16(const unsigned short* g, unsigned short* l) {
  __builtin_amdgcn_global_load_lds(
      (const __attribute__((address_space(1))) unsigned int*)g,
      (__attribute__((address_space(3))) unsigned int*)l, 16, 0, 0);
}

// ---- per-input dtype detector (sampled, vectorized) ------------------------
__global__ __launch_bounds__(256) void detect_all(
    const unsigned short* p0, const unsigned short* p1, const unsigned short* p2,
    const unsigned short* p3, const unsigned short* p4, const unsigned short* p5,
    const unsigned short* p6, int* __restrict__ flags) {
  const unsigned short* ptrs[7] = {p0, p1, p2, p3, p4, p5, p6};
  const int b = blockIdx.x;
  const uint4* p = (const uint4*)ptrs[b];  // 8 words per uint4
  __shared__ int found;
  if (threadIdx.x == 0) found = 0;
  __syncthreads();
  int loc = 0;
#pragma unroll
  for (int it = 0; it < 16; ++it) {
    uint4 v = p[it * 256 + threadIdx.x];
    unsigned wds[4] = {v.x, v.y, v.z, v.w};
#pragma unroll
    for (int q = 0; q < 4; ++q) {
      unsigned lo = wds[q] & 0xFFFFu, hi = wds[q] >> 16;
      if (((lo >> 7) & 0xFFu) == 0xFFu || ((hi >> 7) & 0xFFu) == 0xFFu) loc = 1;
    }
  }
  if (loc) atomicOr(&found, 1);
  __syncthreads();
  if (threadIdx.x == 0) flags[b] = found;
}

// ---- prep: elementwise convert to bf16 -------------------------------------
__global__ __launch_bounds__(256) void cvt_bf16(const void* __restrict__ src,
                                                unsigned short* __restrict__ dst,
                                                int n4, const int* __restrict__ flags, int idx) {
  const bool f32 = flags[idx] != 0;
  int i = blockIdx.x * 256 + threadIdx.x;
  if (i < n4) {
    float4 v = ld4_rt(src, (size_t)i * 4, f32);
    ushort4 o;
    o.x = f2bf(v.x); o.y = f2bf(v.y); o.z = f2bf(v.z); o.w = f2bf(v.w);
    *(ushort4*)&dst[(size_t)i * 4] = o;
  }
}

// ---- prep: all 4 weight transposes in one launch ---------------------------
// z: 0=Wq -> WqkvT, 1=Wk -> WqkvT+KO*2048, 2=Wv -> WqkvT+VO*2048, 3=Wo -> WoT
// All have K=2048 rows; Wk/Wv have N=512 (blocks x>=8 idle-exit).
__global__ __launch_bounds__(256) void transpose_all(
    const void* __restrict__ Wq, const void* __restrict__ Wk,
    const void* __restrict__ Wv, const void* __restrict__ Wo,
    unsigned short* __restrict__ WqkvT, unsigned short* __restrict__ WoT,
    const int* __restrict__ flags) {
  const int z = blockIdx.z;
  const void* srcs[4] = {Wq, Wk, Wv, Wo};
  unsigned short* dsts[4] = {WqkvT, WqkvT + (size_t)KO * 2048, WqkvT + (size_t)VO * 2048, WoT};
  const int Ns[4] = {2048, 512, 512, 2048};
  const int N = Ns[z];
  if (blockIdx.x * 64 >= N) return;
  const void* src = srcs[z];
  unsigned short* dst = dsts[z];
  const bool f32 = flags[3 + z] != 0;
  const int K = 2048;
  __shared__ unsigned short tile[64][65];
  const int t = threadIdx.x;
  const int n0 = blockIdx.x * 64, k0 = blockIdx.y * 64;
  const int cr = t >> 4, cc = (t & 15) * 4;
#pragma unroll
  for (int rr = 0; rr < 4; ++rr) {
    int row = rr * 16 + cr;
    float4 v = ld4_rt(src, (size_t)(k0 + row) * N + n0 + cc, f32);
    tile[row][cc + 0] = f2bf(v.x);
    tile[row][cc + 1] = f2bf(v.y);
    tile[row][cc + 2] = f2bf(v.z);
    tile[row][cc + 3] = f2bf(v.w);
  }
  __syncthreads();
#pragma unroll
  for (int rr = 0; rr < 4; ++rr) {
    int nrow = rr * 16 + cr;
    ushort4 o;
    o.x = tile[cc + 0][nrow];
    o.y = tile[cc + 1][nrow];
    o.z = tile[cc + 2][nrow];
    o.w = tile[cc + 3][nrow];
    *(ushort4*)&dst[(size_t)(n0 + nrow) * K + k0 + cc] = o;
  }
}

// ---- prep: V columns of qkv -> Vt[b][kvh][d=64][L] (bf16) ------------------
__global__ __launch_bounds__(256) void v_to_vt(const unsigned short* __restrict__ qkv,
                                               unsigned short* __restrict__ vt) {
  __shared__ unsigned short tile[64][72];
  const int t = threadIdx.x;
  const int l0 = blockIdx.x * 64;
  const int bk = blockIdx.y;  // b*NKV + kvh
  const int r = t >> 2, c16 = (t & 3) * 16;
  const int b = bk >> 3, kvh = bk & 7;
  const unsigned short* src = &qkv[(size_t)(b * LL + l0 + r) * QS + VO + kvh * 64 + c16];
  *(uint4*)&tile[r][c16] = *(const uint4*)&src[0];
  *(uint4*)&tile[r][c16 + 8] = *(const uint4*)&src[8];
  __syncthreads();
  unsigned short u[16];
#pragma unroll
  for (int j = 0; j < 16; ++j) u[j] = tile[c16 + j][r];
  unsigned short* dst = &vt[((size_t)bk * 64 + r) * LL + l0 + c16];
  *(uint4*)&dst[0] = *(uint4*)&u[0];
  *(uint4*)&dst[8] = *(uint4*)&u[8];
}

// ---------------------------------------------------------------------------
// MFMA GEMM, 3-buffer counted-vmcnt pipeline (T4: never drain to 0 in steady
// state). Per iter t: stage t+2 -> b[(t+2)%3]; ds_read frags b[t%3]; MFMA;
// s_waitcnt vmcnt(4) (t+1's 4 loads landed, t+2's 4 still flying); s_barrier.
// Safety: WAR on b[(t+2)%3]=b[(t-1)%3] -- all waves' iter t-1 ds_reads
// completed before the end-of-(t-1) barrier (lgkm-wait precedes their MFMAs),
// and this wave's stage issues after that barrier. RAW -- each wave waits its
// own vmcnt before the barrier, so after the barrier ALL waves' tile-t loads
// have landed (AITER/HK pattern; m139 precedent).
// FUSE=1: QKV epilogue applies RoPE+RMSNorm in-register to q/k head columns;
// q heads additionally pre-scaled by QSCALE (softmax exp2 fold).
// ---------------------------------------------------------------------------
template <typename CT, int FUSE>
__global__ __launch_bounds__(256) void gemm_mfma(const unsigned short* __restrict__ A,
                                                 const unsigned short* __restrict__ Bt,
                                                 CT* __restrict__ C,
                                                 int M, int N, int K, int lda,
                                                 const void* __restrict__ cosp,
                                                 const void* __restrict__ sinp,
                                                 const int* __restrict__ flags) {
  __shared__ __align__(16) unsigned short As[3][128 * 32];  // row-major [128][32]
  __shared__ __align__(16) unsigned short Bs[3][128 * 32];
  const int t = threadIdx.x;
  const int lane = t & 63, w = t >> 6;
  const int wm = (w >> 1) * 64, wn = (w & 1) * 64;
  const int g = lane >> 4, m16 = lane & 15;
  // XCD swizzle: blocks resident on one XCD get a contiguous chunk of work ids
  const int nwg = gridDim.x * gridDim.y;
  const int orig = blockIdx.y * gridDim.x + blockIdx.x;
  const int swz = (orig & 7) * (nwg >> 3) + (orig >> 3);
  const int m0 = (swz / gridDim.x) * 128, n0 = (swz % gridDim.x) * 128;
  const unsigned short* gA = &A[(size_t)(m0 + (t >> 2)) * lda + (t & 3) * 8];
  const unsigned short* gB = &Bt[(size_t)(n0 + (t >> 2)) * K + (t & 3) * 8];
  const int l8 = t * 8;
  f32x4 acc[4][4] = {};
  const int T = K >> 5;  // K/32 k-steps

#define STAGE(k0_, buf_)                                        \
  do {                                                          \
    glds16(gA + (k0_), &As[buf_][l8]);                          \
    glds16(gA + (size_t)64 * lda + (k0_), &As[buf_][l8 + 2048]);\
    glds16(gB + (k0_), &Bs[buf_][l8]);                          \
    glds16(gB + (size_t)64 * K + (k0_), &Bs[buf_][l8 + 2048]);  \
  } while (0)

  // prologue: tiles 0 and 1 in flight; wait tile 0 only
  STAGE(0, 0);
  STAGE(32, 1);
  asm volatile("s_waitcnt vmcnt(4)" ::: "memory");
  __builtin_amdgcn_s_barrier();

  int buf = 0;
  for (int tt = 0; tt < T; ++tt) {
    const int k0 = tt << 5;
    if (tt + 2 < T) {
      int nb = buf + 2; if (nb >= 3) nb -= 3;
      STAGE(k0 + 64, nb);
    }
    bf16x8 af[4], bfr[4];
#pragma unroll
    for (int i = 0; i < 4; ++i) af[i] = *(const bf16x8*)&As[buf][(wm + i * 16 + m16) * 32 + g * 8];
#pragma unroll
    for (int j = 0; j < 4; ++j) bfr[j] = *(const bf16x8*)&Bs[buf][(wn + j * 16 + m16) * 32 + g * 8];
#pragma unroll
    for (int i = 0; i < 4; ++i)
#pragma unroll
      for (int j = 0; j < 4; ++j)
        acc[i][j] = __builtin_amdgcn_mfma_f32_16x16x32_bf16(af[i], bfr[j], acc[i][j], 0, 0, 0);
    if (tt + 1 < T) {
      if (tt + 2 < T) asm volatile("s_waitcnt vmcnt(4)" ::: "memory");
      else            asm volatile("s_waitcnt vmcnt(0)" ::: "memory");
      __builtin_amdgcn_s_barrier();
    }
    ++buf; if (buf >= 3) buf = 0;
  }
#undef STAGE

  if constexpr (FUSE) {
    const int colbase = n0 + wn;          // 64-aligned -> exactly one head/wave
    if (colbase < VO) {                   // q or k head: RoPE + RMSNorm
      const bool cf = flags[1] != 0, sf = flags[2] != 0;
      const float post = (colbase < KO) ? QSCALE : 1.0f;  // q: fold softmax scale
#pragma unroll
      for (int i = 0; i < 4; ++i)
#pragma unroll
        for (int r = 0; r < 4; ++r) {
          const int row = m0 + wm + i * 16 + g * 4 + r;
          const int l = row & (LL - 1);
          const float c0 = ld1_rt(cosp, l * 32 + m16, cf);
          const float c1 = ld1_rt(cosp, l * 32 + 16 + m16, cf);
          const float s0 = ld1_rt(sinp, l * 32 + m16, sf);
          const float s1 = ld1_rt(sinp, l * 32 + 16 + m16, sf);
          const float x0 = acc[i][0][r], x1 = acc[i][1][r];
          const float x2 = acc[i][2][r], x3 = acc[i][3][r];
          const float r0 = x0 * c0 - x2 * s0;
          const float r1 = x1 * c1 - x3 * s1;
          const float r2 = x2 * c0 + x0 * s0;
          const float r3 = x3 * c1 + x1 * s1;
          float ss = r0 * r0 + r1 * r1 + r2 * r2 + r3 * r3;
#pragma unroll
          for (int off = 1; off < 16; off <<= 1) ss += __shfl_xor(ss, off);
          const float sc = rsqrtf(ss * (1.0f / HD) + EPS) * post;
          CT* cr = &C[(size_t)row * N + colbase + m16];
          store1(cr + 0, r0 * sc);
          store1(cr + 16, r1 * sc);
          store1(cr + 32, r2 * sc);
          store1(cr + 48, r3 * sc);
        }
      return;
    }
  }
#pragma unroll
  for (int i = 0; i < 4; ++i)
#pragma unroll
    for (int j = 0; j < 4; ++j)
#pragma unroll
      for (int r = 0; r < 4; ++r) {
        int row = m0 + wm + i * 16 + g * 4 + r;
        int col = n0 + wn + j * 16 + m16;
        store1(&C[(size_t)row * N + col], acc[i][j][r]);
      }
}

// ---------------------------------------------------------------------------
// MFMA causal GQA flash attention with STATIC-MAX softmax.
// q pre-scaled by QSCALE in the GEMM epilogue => p = 2^(S - SM_BIAS).
// ---------------------------------------------------------------------------
__global__ __launch_bounds__(256) void attn_mfma(unsigned short* __restrict__ qkv,
                                                 const unsigned short* __restrict__ vt) {
  __shared__ __align__(16) unsigned short Ks[2][64 * 64];  // [key][d], chunk-swizzled
  __shared__ __align__(16) unsigned short Vs[2][64 * 64];  // [d][key], chunk-swizzled
  __shared__ __align__(16) unsigned short Pt[4][64 * 16];  // per-wave P^T [key][qrow]
  const int t = threadIdx.x, lane = t & 63, w = t >> 6;
  const int g = lane >> 4, m16 = lane & 15;
  const int h = blockIdx.x, b = blockIdx.y;
  const int qt = (LL / 64 - 1) - blockIdx.z;  // longest blocks dispatch first
  const int kvh = h >> 2;
  const int q0 = qt * 64, qr0 = q0 + w * 16;

  bf16x8 qf0, qf1;
  {
    const unsigned short* qrow = &qkv[(size_t)(b * LL + qr0 + m16) * QS + h * 64 + g * 8];
    qf0 = *(const bf16x8*)&qrow[0];
    qf1 = *(const bf16x8*)&qrow[32];
  }
  f32x4 Oacc[4] = {};
  float lrow[4] = {0.f, 0.f, 0.f, 0.f};

  const int lr = lane >> 3;            // row within the 8-row group
  const int lc = (lane & 7) ^ lr;      // swizzled source 16B chunk
  const unsigned short* gK = &qkv[(size_t)(b * LL) * QS + KO + kvh * 64 + lc * 8];
  const unsigned short* gV = &vt[((size_t)(b * NKV + kvh) * 64 + w * 16 + lr) * LL + lc * 8];
  const int dbase = w * 1024 + lane * 8;  // LDS dest (shorts): wave-linear
  const int nIter = q0 / 64 + 1;

  // prologue: stage tile 0 into buffer 0
#pragma unroll
  for (int c = 0; c < 2; ++c) {
    glds16(gK + (size_t)(w * 16 + c * 8 + lr) * QS, &Ks[0][dbase + c * 512]);
    glds16(gV + (size_t)c * 8 * LL, &Vs[0][dbase + c * 512]);
  }
  __syncthreads();  // vmcnt(0) drain included

  const int sw8 = (m16 & 7) * 8;  // read-side chunk swizzle (shorts)
  for (int it = 0; it < nIter; ++it) {
    const int j0 = it * 64;
    const int cur = it & 1;
    if (it + 1 < nIter) {  // prefetch next tile into the other buffer
      const int nj = j0 + 64;
#pragma unroll
      for (int c = 0; c < 2; ++c) {
        glds16(gK + (size_t)(nj + w * 16 + c * 8 + lr) * QS, &Ks[cur ^ 1][dbase + c * 512]);
        glds16(gV + (size_t)c * 8 * LL + nj, &Vs[cur ^ 1][dbase + c * 512]);
      }
    }
    const unsigned short* KsB = Ks[cur];
    const unsigned short* VsB = Vs[cur];

    // S = Q K^T
    f32x4 S[4];
#pragma unroll
    for (int jt = 0; jt < 4; ++jt) {
      const int rb = (jt * 16 + m16) * 64;
      bf16x8 kf0 = *(const bf16x8*)&KsB[rb + ((g * 8) ^ sw8)];
      bf16x8 kf1 = *(const bf16x8*)&KsB[rb + (((g + 4) * 8) ^ sw8)];
      f32x4 z = {0.f, 0.f, 0.f, 0.f};
      z = __builtin_amdgcn_mfma_f32_16x16x32_bf16(qf0, kf0, z, 0, 0, 0);
      S[jt] = __builtin_amdgcn_mfma_f32_16x16x32_bf16(qf1, kf1, z, 0, 0, 0);
    }
    // static-max softmax: p = 2^(S - SM_BIAS); mask only on the diagonal tile
    if (j0 == q0) {
#pragma unroll
      for (int jt = 0; jt < 4; ++jt)
#pragma unroll
        for (int r = 0; r < 4; ++r) {
          int col = q0 + jt * 16 + m16;
          int row = qr0 + g * 4 + r;
          float p = exp2f(S[jt][r] - SM_BIAS);
          p = (col <= row) ? p : 0.f;
          S[jt][r] = p;
          lrow[r] += p;
        }
    } else {
#pragma unroll
      for (int jt = 0; jt < 4; ++jt)
#pragma unroll
        for (int r = 0; r < 4; ++r) {
          float p = exp2f(S[jt][r] - SM_BIAS);
          S[jt][r] = p;
          lrow[r] += p;
        }
    }
    // P -> per-wave Pt (transposed [key][qrow]): 4 vector b64 writes
#pragma unroll
    for (int jt = 0; jt < 4; ++jt) {
      ushort4 pw;
      pw.x = f2bf(S[jt][0]); pw.y = f2bf(S[jt][1]);
      pw.z = f2bf(S[jt][2]); pw.w = f2bf(S[jt][3]);
      *(ushort4*)&Pt[w][(jt * 16 + m16) * 16 + g * 4] = pw;
    }
    // A-fragment reload via hardware transpose read (lane stride 8 B in-group)
    s16x4 a0, a1, b0, b1;
    {
      __attribute__((address_space(3))) unsigned short* p3 =
          (__attribute__((address_space(3))) unsigned short*)&Pt[w][g * 128 + m16 * 4];
      unsigned paddr = (unsigned)(size_t)p3;
      asm volatile(
          "s_waitcnt lgkmcnt(0)\n\t"
          "ds_read_b64_tr_b16 %0, %4\n\t"
          "ds_read_b64_tr_b16 %1, %4 offset:128\n\t"
          "ds_read_b64_tr_b16 %2, %4 offset:1024\n\t"
          "ds_read_b64_tr_b16 %3, %4 offset:1152\n\t"
          "s_waitcnt lgkmcnt(0)"
          : "=&v"(a0), "=&v"(a1), "=&v"(b0), "=&v"(b1)
          : "v"(paddr)
          : "memory");
      __builtin_amdgcn_sched_barrier(0);  // rule #18: keep MFMAs below the wait
    }
    bf16x8 pf0 = __builtin_shufflevector(a0, a1, 0, 1, 2, 3, 4, 5, 6, 7);
    bf16x8 pf1 = __builtin_shufflevector(b0, b1, 0, 1, 2, 3, 4, 5, 6, 7);
    // O += P V
#pragma unroll
    for (int dt = 0; dt < 4; ++dt) {
      const int rb = (dt * 16 + m16) * 64;
      bf16x8 vf0 = *(const bf16x8*)&VsB[rb + ((g * 8) ^ sw8)];
      bf16x8 vf1 = *(const bf16x8*)&VsB[rb + (((g + 4) * 8) ^ sw8)];
      Oacc[dt] = __builtin_amdgcn_mfma_f32_16x16x32_bf16(pf0, vf0, Oacc[dt], 0, 0, 0);
      Oacc[dt] = __builtin_amdgcn_mfma_f32_16x16x32_bf16(pf1, vf1, Oacc[dt], 0, 0, 0);
    }
    // single barrier per tile: syncs waves AND drains prefetch vmcnt
    __syncthreads();
  }
  // epilogue: reduce l across the 16-lane column groups, normalize, store
  float inv[4];
#pragma unroll
  for (int r = 0; r < 4; ++r) {
#pragma unroll
    for (int off = 1; off < 16; off <<= 1) lrow[r] += __shfl_xor(lrow[r], off);
    inv[r] = 1.0f / lrow[r];
  }
#pragma unroll
  for (int dt = 0; dt < 4; ++dt)
#pragma unroll
    for (int r = 0; r < 4; ++r) {
      int row = qr0 + g * 4 + r;
      qkv[(size_t)(b * LL + row) * QS + h * 64 + dt * 16 + m16] = f2bf(Oacc[dt][r] * inv[r]);
    }
}

// ---------------------------------------------------------------------------
extern "C" void kernel_launch(void* const* d_in, const int* in_sizes, int n_in,
                              void* d_out, int out_size, void* d_ws, size_t ws_size,
                              hipStream_t stream) {
  const void* x = d_in[0];
  const void* cosp = d_in[1];
  const void* sinp = d_in[2];
  const void* Wq = d_in[3];
  const void* Wk = d_in[4];
  const void* Wv = d_in[5];
  const void* Wo = d_in[6];
  float* out = (float*)d_out;

  // ws (bf16): xb [4096][2048] | qkvb [4096][3072] | WqkvT [3072][2048]
  //          | WoT [2048][2048] | Vt [2*8][64][2048]
  char* w0 = (char*)d_ws;
  int* flags = (int*)w0;
  unsigned short* xb = (unsigned short*)(w0 + 256);
  unsigned short* qkvb = xb + (size_t)MM * 2048;
  unsigned short* WqkvT = qkvb + (size_t)MM * QS;
  unsigned short* WoT = WqkvT + (size_t)QS * 2048;
  unsigned short* vt = WoT + (size_t)2048 * 2048;

  detect_all<<<7, 256, 0, stream>>>(
      (const unsigned short*)x, (const unsigned short*)cosp, (const unsigned short*)sinp,
      (const unsigned short*)Wq, (const unsigned short*)Wk, (const unsigned short*)Wv,
      (const unsigned short*)Wo, flags);
  cvt_bf16<<<MM * 2048 / 4 / 256, 256, 0, stream>>>(x, xb, MM * 2048 / 4, flags, 0);
  transpose_all<<<dim3(32, 32, 4), 256, 0, stream>>>(Wq, Wk, Wv, Wo, WqkvT, WoT, flags);
  // fused QKV projection + RoPE + RMSNorm epilogue on q/k heads (q pre-scaled)
  gemm_mfma<unsigned short, 1><<<dim3(QS / 128, MM / 128), 256, 0, stream>>>(
      xb, WqkvT, qkvb, MM, QS, 2048, 2048, cosp, sinp, flags);
  // V^T materialization (V is untouched by rope/rms)
  v_to_vt<<<dim3(LL / 64, BB * NKV), 256, 0, stream>>>(qkvb, vt);
  // causal GQA attention, O in-place into q columns; longest qt first
  attn_mfma<<<dim3(NH, BB, LL / 64), 256, 0, stream>>>(qkvb, vt);
  // output projection: qkv's q columns (lda=3072) @ WoT -> f32 out
  gemm_mfma<float, 0><<<dim3(2048 / 128, MM / 128), 256, 0, stream>>>(
      qkvb, WoT, out, MM, 2048, 2048, QS, nullptr, nullptr, nullptr);
}

// Round 5
// 317.091 us; speedup vs baseline: 1.1900x; 1.0327x over previous
//
#include <hip/hip_runtime.h>
#include <hip/hip_bf16.h>
#include <cstdint>
#include <cstddef>

#define D_MODEL 2048
#define NH 32
#define NKV 8
#define HD 64
#define BB 2
#define LL 2048
#define EPS 1e-6f
#define MM (BB * LL)   // 4096
#define QS 3072        // fused qkv row stride
#define KO 2048        // k column offset in qkv
#define VO 2560        // v column offset in qkv
// softmax fold: q pre-scaled by 0.125*log2(e); p = 2^(S - 8*log2(e))
#define QSCALE 0.18033688f
#define SM_BIAS 11.5415603f

typedef __hip_bfloat16 bf16;
typedef short bf16x8 __attribute__((ext_vector_type(8)));
typedef short s16x4 __attribute__((ext_vector_type(4)));
typedef float f32x4 __attribute__((ext_vector_type(4)));

// ---- dtype helpers ---------------------------------------------------------
__device__ inline float4 ld_bf4u(const unsigned short* p) {
  const ushort4 u = *(const ushort4*)p;
  float4 r;
  r.x = __uint_as_float(((unsigned)u.x) << 16);
  r.y = __uint_as_float(((unsigned)u.y) << 16);
  r.z = __uint_as_float(((unsigned)u.z) << 16);
  r.w = __uint_as_float(((unsigned)u.w) << 16);
  return r;
}
__device__ inline float4 ld4_rt(const void* p, size_t i, bool f32) {
  if (f32) return *(const float4*)((const float*)p + i);
  return ld_bf4u((const unsigned short*)p + i);
}
__device__ inline float ld1_rt(const void* p, size_t i, bool f32) {
  if (f32) return ((const float*)p)[i];
  unsigned short u = ((const unsigned short*)p)[i];
  return __uint_as_float(((unsigned)u) << 16);
}
__device__ inline unsigned short f2bf(float f) {
  bf16 h = __float2bfloat16(f);  // RNE
  return *reinterpret_cast<unsigned short*>(&h);
}
__device__ inline float bfu2f(unsigned short u) {
  return __uint_as_float(((unsigned)u) << 16);
}
__device__ inline void store1(float* p, float v) { *p = v; }
__device__ inline void store1(unsigned short* p, float v) { *p = f2bf(v); }

// async global->LDS, 16 B per lane; LDS dest must be wave-uniform base + lane*16
__device__ inline void glds16(const unsigned short* g, unsigned short* l) {
  __builtin_amdgcn_global_load_lds(
      (const __attribute__((address_space(1))) unsigned int*)g,
      (__attribute__((address_space(3))) unsigned int*)l, 16, 0, 0);
}

// ---- per-input dtype detector (sampled, vectorized) ------------------------
__global__ __launch_bounds__(256) void detect_all(
    const unsigned short* p0, const unsigned short* p1, const unsigned short* p2,
    const unsigned short* p3, const unsigned short* p4, const unsigned short* p5,
    const unsigned short* p6, int* __restrict__ flags) {
  const unsigned short* ptrs[7] = {p0, p1, p2, p3, p4, p5, p6};
  const int b = blockIdx.x;
  const uint4* p = (const uint4*)ptrs[b];  // 8 words per uint4
  __shared__ int found;
  if (threadIdx.x == 0) found = 0;
  __syncthreads();
  int loc = 0;
#pragma unroll
  for (int it = 0; it < 16; ++it) {
    uint4 v = p[it * 256 + threadIdx.x];
    unsigned wds[4] = {v.x, v.y, v.z, v.w};
#pragma unroll
    for (int q = 0; q < 4; ++q) {
      unsigned lo = wds[q] & 0xFFFFu, hi = wds[q] >> 16;
      if (((lo >> 7) & 0xFFu) == 0xFFu || ((hi >> 7) & 0xFFu) == 0xFFu) loc = 1;
    }
  }
  if (loc) atomicOr(&found, 1);
  __syncthreads();
  if (threadIdx.x == 0) flags[b] = found;
}

// ---- prep: elementwise convert to bf16 -------------------------------------
__global__ __launch_bounds__(256) void cvt_bf16(const void* __restrict__ src,
                                                unsigned short* __restrict__ dst,
                                                int n4, const int* __restrict__ flags, int idx) {
  const bool f32 = flags[idx] != 0;
  int i = blockIdx.x * 256 + threadIdx.x;
  if (i < n4) {
    float4 v = ld4_rt(src, (size_t)i * 4, f32);
    ushort4 o;
    o.x = f2bf(v.x); o.y = f2bf(v.y); o.z = f2bf(v.z); o.w = f2bf(v.w);
    *(ushort4*)&dst[(size_t)i * 4] = o;
  }
}

// ---- prep: all 4 weight transposes in one launch ---------------------------
__global__ __launch_bounds__(256) void transpose_all(
    const void* __restrict__ Wq, const void* __restrict__ Wk,
    const void* __restrict__ Wv, const void* __restrict__ Wo,
    unsigned short* __restrict__ WqkvT, unsigned short* __restrict__ WoT,
    const int* __restrict__ flags) {
  const int z = blockIdx.z;
  const void* srcs[4] = {Wq, Wk, Wv, Wo};
  unsigned short* dsts[4] = {WqkvT, WqkvT + (size_t)KO * 2048, WqkvT + (size_t)VO * 2048, WoT};
  const int Ns[4] = {2048, 512, 512, 2048};
  const int N = Ns[z];
  if (blockIdx.x * 64 >= N) return;
  const void* src = srcs[z];
  unsigned short* dst = dsts[z];
  const bool f32 = flags[3 + z] != 0;
  const int K = 2048;
  __shared__ unsigned short tile[64][65];
  const int t = threadIdx.x;
  const int n0 = blockIdx.x * 64, k0 = blockIdx.y * 64;
  const int cr = t >> 4, cc = (t & 15) * 4;
#pragma unroll
  for (int rr = 0; rr < 4; ++rr) {
    int row = rr * 16 + cr;
    float4 v = ld4_rt(src, (size_t)(k0 + row) * N + n0 + cc, f32);
    tile[row][cc + 0] = f2bf(v.x);
    tile[row][cc + 1] = f2bf(v.y);
    tile[row][cc + 2] = f2bf(v.z);
    tile[row][cc + 3] = f2bf(v.w);
  }
  __syncthreads();
#pragma unroll
  for (int rr = 0; rr < 4; ++rr) {
    int nrow = rr * 16 + cr;
    ushort4 o;
    o.x = tile[cc + 0][nrow];
    o.y = tile[cc + 1][nrow];
    o.z = tile[cc + 2][nrow];
    o.w = tile[cc + 3][nrow];
    *(ushort4*)&dst[(size_t)(n0 + nrow) * K + k0 + cc] = o;
  }
}

// ---------------------------------------------------------------------------
// MFMA GEMM, 3-buffer counted-vmcnt pipeline + bank-conflict-free LDS.
// LDS chunk swizzle (both-sides, rule #21): row r of a [128][32] tile holds
// global 16B-chunk c at slot c ^ ((r>>1)&3). Stage: thread t (row t>>2) loads
// source chunk (t&3)^((t>>3)&3) into linear dest. Read: lane (g,m16) reads
// slot g^((m16>>1)&3) -- per 16-lane phase group banks land 2 lanes per
// 4-bank set (was 8-way: bank = (row&1)*16+chunk*4 with g constant in-group).
// FUSE=1: QKV epilogue: RoPE+RMSNorm on q/k heads (q pre-scaled by QSCALE);
// V heads are written TRANSPOSED directly to vt[b][kvh][d][L] (qkvb V columns
// are never written or read -- saves the v_to_vt kernel + 24 MB traffic).
// ---------------------------------------------------------------------------
template <typename CT, int FUSE>
__global__ __launch_bounds__(256) void gemm_mfma(const unsigned short* __restrict__ A,
                                                 const unsigned short* __restrict__ Bt,
                                                 CT* __restrict__ C,
                                                 int M, int N, int K, int lda,
                                                 const void* __restrict__ cosp,
                                                 const void* __restrict__ sinp,
                                                 const int* __restrict__ flags,
                                                 unsigned short* __restrict__ vt) {
  __shared__ __align__(16) unsigned short As[3][128 * 32];  // [128][32], chunk-swizzled
  __shared__ __align__(16) unsigned short Bs[3][128 * 32];
  const int t = threadIdx.x;
  const int lane = t & 63, w = t >> 6;
  const int wm = (w >> 1) * 64, wn = (w & 1) * 64;
  const int g = lane >> 4, m16 = lane & 15;
  // XCD swizzle: blocks resident on one XCD get a contiguous chunk of work ids
  const int nwg = gridDim.x * gridDim.y;
  const int orig = blockIdx.y * gridDim.x + blockIdx.x;
  const int swz = (orig & 7) * (nwg >> 3) + (orig >> 3);
  const int m0 = (swz / gridDim.x) * 128, n0 = (swz % gridDim.x) * 128;
  // staged source chunk for this thread (inverse of the read-side XOR)
  const int csw = (t & 3) ^ ((t >> 3) & 3);
  const unsigned short* gA = &A[(size_t)(m0 + (t >> 2)) * lda + csw * 8];
  const unsigned short* gB = &Bt[(size_t)(n0 + (t >> 2)) * K + csw * 8];
  const int l8 = t * 8;
  // read-side swizzled chunk (shorts offset within a 32-short row)
  const int cs8 = (g ^ ((m16 >> 1) & 3)) * 8;
  f32x4 acc[4][4] = {};
  const int T = K >> 5;  // K/32 k-steps

#define STAGE(k0_, buf_)                                        \
  do {                                                          \
    glds16(gA + (k0_), &As[buf_][l8]);                          \
    glds16(gA + (size_t)64 * lda + (k0_), &As[buf_][l8 + 2048]);\
    glds16(gB + (k0_), &Bs[buf_][l8]);                          \
    glds16(gB + (size_t)64 * K + (k0_), &Bs[buf_][l8 + 2048]);  \
  } while (0)

  // prologue: tiles 0 and 1 in flight; wait tile 0 only
  STAGE(0, 0);
  STAGE(32, 1);
  asm volatile("s_waitcnt vmcnt(4)" ::: "memory");
  __builtin_amdgcn_s_barrier();

  int buf = 0;
  for (int tt = 0; tt < T; ++tt) {
    const int k0 = tt << 5;
    if (tt + 2 < T) {
      int nb = buf + 2; if (nb >= 3) nb -= 3;
      STAGE(k0 + 64, nb);
    }
    bf16x8 af[4], bfr[4];
#pragma unroll
    for (int i = 0; i < 4; ++i) af[i] = *(const bf16x8*)&As[buf][(wm + i * 16 + m16) * 32 + cs8];
#pragma unroll
    for (int j = 0; j < 4; ++j) bfr[j] = *(const bf16x8*)&Bs[buf][(wn + j * 16 + m16) * 32 + cs8];
#pragma unroll
    for (int i = 0; i < 4; ++i)
#pragma unroll
      for (int j = 0; j < 4; ++j)
        acc[i][j] = __builtin_amdgcn_mfma_f32_16x16x32_bf16(af[i], bfr[j], acc[i][j], 0, 0, 0);
    if (tt + 1 < T) {
      if (tt + 2 < T) asm volatile("s_waitcnt vmcnt(4)" ::: "memory");
      else            asm volatile("s_waitcnt vmcnt(0)" ::: "memory");
      __builtin_amdgcn_s_barrier();
    }
    ++buf; if (buf >= 3) buf = 0;
  }
#undef STAGE

  if constexpr (FUSE) {
    const int colbase = n0 + wn;          // 64-aligned -> exactly one head/wave
    if (colbase < VO) {                   // q or k head: RoPE + RMSNorm
      const bool cf = flags[1] != 0, sf = flags[2] != 0;
      const float post = (colbase < KO) ? QSCALE : 1.0f;  // q: fold softmax scale
#pragma unroll
      for (int i = 0; i < 4; ++i)
#pragma unroll
        for (int r = 0; r < 4; ++r) {
          const int row = m0 + wm + i * 16 + g * 4 + r;
          const int l = row & (LL - 1);
          const float c0 = ld1_rt(cosp, l * 32 + m16, cf);
          const float c1 = ld1_rt(cosp, l * 32 + 16 + m16, cf);
          const float s0 = ld1_rt(sinp, l * 32 + m16, sf);
          const float s1 = ld1_rt(sinp, l * 32 + 16 + m16, sf);
          const float x0 = acc[i][0][r], x1 = acc[i][1][r];
          const float x2 = acc[i][2][r], x3 = acc[i][3][r];
          const float r0 = x0 * c0 - x2 * s0;
          const float r1 = x1 * c1 - x3 * s1;
          const float r2 = x2 * c0 + x0 * s0;
          const float r3 = x3 * c1 + x1 * s1;
          float ss = r0 * r0 + r1 * r1 + r2 * r2 + r3 * r3;
#pragma unroll
          for (int off = 1; off < 16; off <<= 1) ss += __shfl_xor(ss, off);
          const float sc = rsqrtf(ss * (1.0f / HD) + EPS) * post;
          CT* cr = &C[(size_t)row * N + colbase + m16];
          store1(cr + 0, r0 * sc);
          store1(cr + 16, r1 * sc);
          store1(cr + 32, r2 * sc);
          store1(cr + 48, r3 * sc);
        }
    } else {
      // V head: write transposed into vt[b][kvh][d=64][L]
      const int bb = (m0 + wm) >> 11;            // row block's batch
      const int lb = (m0 + wm) & (LL - 1);       // row block's l base
      const int kvh = (colbase - VO) >> 6;
      unsigned short* vb = vt + (size_t)(bb * NKV + kvh) * 64 * LL;
#pragma unroll
      for (int j = 0; j < 4; ++j)
#pragma unroll
        for (int i = 0; i < 4; ++i) {
          ushort4 pw;
          pw.x = f2bf(acc[i][j][0]); pw.y = f2bf(acc[i][j][1]);
          pw.z = f2bf(acc[i][j][2]); pw.w = f2bf(acc[i][j][3]);
          *(ushort4*)&vb[(size_t)(j * 16 + m16) * LL + lb + i * 16 + g * 4] = pw;
        }
    }
    return;
  }
#pragma unroll
  for (int i = 0; i < 4; ++i)
#pragma unroll
    for (int j = 0; j < 4; ++j)
#pragma unroll
      for (int r = 0; r < 4; ++r) {
        int row = m0 + wm + i * 16 + g * 4 + r;
        int col = n0 + wn + j * 16 + m16;
        store1(&C[(size_t)row * N + col], acc[i][j][r]);
      }
}

// ---------------------------------------------------------------------------
// MFMA causal GQA flash attention with STATIC-MAX softmax.
// q pre-scaled by QSCALE in the GEMM epilogue => p = 2^(S - SM_BIAS),
// computed with the NATIVE v_exp_f32 (bare builtin; libm exp2f's safe path
// cost +4 us in R4).
// ---------------------------------------------------------------------------
__global__ __launch_bounds__(256) void attn_mfma(unsigned short* __restrict__ qkv,
                                                 const unsigned short* __restrict__ vt) {
  __shared__ __align__(16) unsigned short Ks[2][64 * 64];  // [key][d], chunk-swizzled
  __shared__ __align__(16) unsigned short Vs[2][64 * 64];  // [d][key], chunk-swizzled
  __shared__ __align__(16) unsigned short Pt[4][64 * 16];  // per-wave P^T [key][qrow]
  const int t = threadIdx.x, lane = t & 63, w = t >> 6;
  const int g = lane >> 4, m16 = lane & 15;
  const int h = blockIdx.x, b = blockIdx.y;
  const int qt = (LL / 64 - 1) - blockIdx.z;  // longest blocks dispatch first
  const int kvh = h >> 2;
  const int q0 = qt * 64, qr0 = q0 + w * 16;

  bf16x8 qf0, qf1;
  {
    const unsigned short* qrow = &qkv[(size_t)(b * LL + qr0 + m16) * QS + h * 64 + g * 8];
    qf0 = *(const bf16x8*)&qrow[0];
    qf1 = *(const bf16x8*)&qrow[32];
  }
  f32x4 Oacc[4] = {};
  float lrow[4] = {0.f, 0.f, 0.f, 0.f};

  const int lr = lane >> 3;            // row within the 8-row group
  const int lc = (lane & 7) ^ lr;      // swizzled source 16B chunk
  const unsigned short* gK = &qkv[(size_t)(b * LL) * QS + KO + kvh * 64 + lc * 8];
  const unsigned short* gV = &vt[((size_t)(b * NKV + kvh) * 64 + w * 16 + lr) * LL + lc * 8];
  const int dbase = w * 1024 + lane * 8;  // LDS dest (shorts): wave-linear
  const int nIter = q0 / 64 + 1;

  // prologue: stage tile 0 into buffer 0
#pragma unroll
  for (int c = 0; c < 2; ++c) {
    glds16(gK + (size_t)(w * 16 + c * 8 + lr) * QS, &Ks[0][dbase + c * 512]);
    glds16(gV + (size_t)c * 8 * LL, &Vs[0][dbase + c * 512]);
  }
  __syncthreads();  // vmcnt(0) drain included

  const int sw8 = (m16 & 7) * 8;  // read-side chunk swizzle (shorts)
  for (int it = 0; it < nIter; ++it) {
    const int j0 = it * 64;
    const int cur = it & 1;
    if (it + 1 < nIter) {  // prefetch next tile into the other buffer
      const int nj = j0 + 64;
#pragma unroll
      for (int c = 0; c < 2; ++c) {
        glds16(gK + (size_t)(nj + w * 16 + c * 8 + lr) * QS, &Ks[cur ^ 1][dbase + c * 512]);
        glds16(gV + (size_t)c * 8 * LL + nj, &Vs[cur ^ 1][dbase + c * 512]);
      }
    }
    const unsigned short* KsB = Ks[cur];
    const unsigned short* VsB = Vs[cur];

    // S = Q K^T
    f32x4 S[4];
#pragma unroll
    for (int jt = 0; jt < 4; ++jt) {
      const int rb = (jt * 16 + m16) * 64;
      bf16x8 kf0 = *(const bf16x8*)&KsB[rb + ((g * 8) ^ sw8)];
      bf16x8 kf1 = *(const bf16x8*)&KsB[rb + (((g + 4) * 8) ^ sw8)];
      f32x4 z = {0.f, 0.f, 0.f, 0.f};
      z = __builtin_amdgcn_mfma_f32_16x16x32_bf16(qf0, kf0, z, 0, 0, 0);
      S[jt] = __builtin_amdgcn_mfma_f32_16x16x32_bf16(qf1, kf1, z, 0, 0, 0);
    }
    // static-max softmax: p = 2^(S - SM_BIAS); mask only on the diagonal tile
    if (j0 == q0) {
#pragma unroll
      for (int jt = 0; jt < 4; ++jt)
#pragma unroll
        for (int r = 0; r < 4; ++r) {
          int col = q0 + jt * 16 + m16;
          int row = qr0 + g * 4 + r;
          float p = __builtin_amdgcn_exp2f(S[jt][r] - SM_BIAS);
          p = (col <= row) ? p : 0.f;
          S[jt][r] = p;
          lrow[r] += p;
        }
    } else {
#pragma unroll
      for (int jt = 0; jt < 4; ++jt)
#pragma unroll
        for (int r = 0; r < 4; ++r) {
          float p = __builtin_amdgcn_exp2f(S[jt][r] - SM_BIAS);
          S[jt][r] = p;
          lrow[r] += p;
        }
    }
    // P -> per-wave Pt (transposed [key][qrow]): 4 vector b64 writes
#pragma unroll
    for (int jt = 0; jt < 4; ++jt) {
      ushort4 pw;
      pw.x = f2bf(S[jt][0]); pw.y = f2bf(S[jt][1]);
      pw.z = f2bf(S[jt][2]); pw.w = f2bf(S[jt][3]);
      *(ushort4*)&Pt[w][(jt * 16 + m16) * 16 + g * 4] = pw;
    }
    // A-fragment reload via hardware transpose read (lane stride 8 B in-group)
    s16x4 a0, a1, b0, b1;
    {
      __attribute__((address_space(3))) unsigned short* p3 =
          (__attribute__((address_space(3))) unsigned short*)&Pt[w][g * 128 + m16 * 4];
      unsigned paddr = (unsigned)(size_t)p3;
      asm volatile(
          "s_waitcnt lgkmcnt(0)\n\t"
          "ds_read_b64_tr_b16 %0, %4\n\t"
          "ds_read_b64_tr_b16 %1, %4 offset:128\n\t"
          "ds_read_b64_tr_b16 %2, %4 offset:1024\n\t"
          "ds_read_b64_tr_b16 %3, %4 offset:1152\n\t"
          "s_waitcnt lgkmcnt(0)"
          : "=&v"(a0), "=&v"(a1), "=&v"(b0), "=&v"(b1)
          : "v"(paddr)
          : "memory");
      __builtin_amdgcn_sched_barrier(0);  // rule #18: keep MFMAs below the wait
    }
    bf16x8 pf0 = __builtin_shufflevector(a0, a1, 0, 1, 2, 3, 4, 5, 6, 7);
    bf16x8 pf1 = __builtin_shufflevector(b0, b1, 0, 1, 2, 3, 4, 5, 6, 7);
    // O += P V
#pragma unroll
    for (int dt = 0; dt < 4; ++dt) {
      const int rb = (dt * 16 + m16) * 64;
      bf16x8 vf0 = *(const bf16x8*)&VsB[rb + ((g * 8) ^ sw8)];
      bf16x8 vf1 = *(const bf16x8*)&VsB[rb + (((g + 4) * 8) ^ sw8)];
      Oacc[dt] = __builtin_amdgcn_mfma_f32_16x16x32_bf16(pf0, vf0, Oacc[dt], 0, 0, 0);
      Oacc[dt] = __builtin_amdgcn_mfma_f32_16x16x32_bf16(pf1, vf1, Oacc[dt], 0, 0, 0);
    }
    // single barrier per tile: syncs waves AND drains prefetch vmcnt
    __syncthreads();
  }
  // epilogue: reduce l across the 16-lane column groups, normalize, store
  float inv[4];
#pragma unroll
  for (int r = 0; r < 4; ++r) {
#pragma unroll
    for (int off = 1; off < 16; off <<= 1) lrow[r] += __shfl_xor(lrow[r], off);
    inv[r] = 1.0f / lrow[r];
  }
#pragma unroll
  for (int dt = 0; dt < 4; ++dt)
#pragma unroll
    for (int r = 0; r < 4; ++r) {
      int row = qr0 + g * 4 + r;
      qkv[(size_t)(b * LL + row) * QS + h * 64 + dt * 16 + m16] = f2bf(Oacc[dt][r] * inv[r]);
    }
}

// ---------------------------------------------------------------------------
extern "C" void kernel_launch(void* const* d_in, const int* in_sizes, int n_in,
                              void* d_out, int out_size, void* d_ws, size_t ws_size,
                              hipStream_t stream) {
  const void* x = d_in[0];
  const void* cosp = d_in[1];
  const void* sinp = d_in[2];
  const void* Wq = d_in[3];
  const void* Wk = d_in[4];
  const void* Wv = d_in[5];
  const void* Wo = d_in[6];
  float* out = (float*)d_out;

  // ws (bf16): xb [4096][2048] | qkvb [4096][3072] | WqkvT [3072][2048]
  //          | WoT [2048][2048] | Vt [2*8][64][2048]
  char* w0 = (char*)d_ws;
  int* flags = (int*)w0;
  unsigned short* xb = (unsigned short*)(w0 + 256);
  unsigned short* qkvb = xb + (size_t)MM * 2048;
  unsigned short* WqkvT = qkvb + (size_t)MM * QS;
  unsigned short* WoT = WqkvT + (size_t)QS * 2048;
  unsigned short* vt = WoT + (size_t)2048 * 2048;

  detect_all<<<7, 256, 0, stream>>>(
      (const unsigned short*)x, (const unsigned short*)cosp, (const unsigned short*)sinp,
      (const unsigned short*)Wq, (const unsigned short*)Wk, (const unsigned short*)Wv,
      (const unsigned short*)Wo, flags);
  cvt_bf16<<<MM * 2048 / 4 / 256, 256, 0, stream>>>(x, xb, MM * 2048 / 4, flags, 0);
  transpose_all<<<dim3(32, 32, 4), 256, 0, stream>>>(Wq, Wk, Wv, Wo, WqkvT, WoT, flags);
  // fused QKV projection + RoPE/RMSNorm epilogue (q pre-scaled) + V^T to vt
  gemm_mfma<unsigned short, 1><<<dim3(QS / 128, MM / 128), 256, 0, stream>>>(
      xb, WqkvT, qkvb, MM, QS, 2048, 2048, cosp, sinp, flags, vt);
  // causal GQA attention, O in-place into q columns; longest qt first
  attn_mfma<<<dim3(NH, BB, LL / 64), 256, 0, stream>>>(qkvb, vt);
  // output projection: qkv's q columns (lda=3072) @ WoT -> f32 out
  gemm_mfma<float, 0><<<dim3(2048 / 128, MM / 128), 256, 0, stream>>>(
      qkvb, WoT, out, MM, 2048, 2048, QS, nullptr, nullptr, nullptr, nullptr);
}